// Round 4
// baseline (53.156 us; speedup 1.0000x reference)
//
#include <hip/hip_runtime.h>

#define NPIX 5184   // 72*72
#define KDIM 256
#define OUTHW 224
#define BT 256      // block tile
#define NT 21       // 21*256 = 5376 padded
#define NPAD (NT*BT)
#define NWG (NT*NT) // 441
#define NKT 4       // K=256 in chunks of 64
#define MATB (BT*128)   // 32 KiB: 256 rows x 64 bf16 (128 B)
#define BUFB (2*MATB)   // 64 KiB per double-buffer slot (A+B)

typedef __bf16 bf16x8 __attribute__((ext_vector_type(8)));
typedef float  f32x4  __attribute__((ext_vector_type(4)));

__device__ inline unsigned short f2bf(float f) {
    unsigned int b = __float_as_uint(f);
    b += 0x7FFFu + ((b >> 16) & 1u);     // round-to-nearest-even
    return (unsigned short)(b >> 16);
}
__device__ inline unsigned int fmono(float f) {
    unsigned int b = __float_as_uint(f);
    return b ^ ((b >> 31) ? 0xFFFFFFFFu : 0x80000000u);
}
__device__ inline float funmono(unsigned int u) {
    unsigned int b = u ^ ((u >> 31) ? 0x80000000u : 0xFFFFFFFFu);
    return __uint_as_float(b);
}

// fp32 -> bf16 with zero-padding to NPAD rows; also inits sums and max.
__global__ void convert_pad_bf16(const float* __restrict__ x,
                                 unsigned short* __restrict__ Abf,
                                 unsigned short* __restrict__ Bbf,
                                 float* __restrict__ sums,
                                 unsigned int* __restrict__ max_u) {
    int i = blockIdx.x * blockDim.x + threadIdx.x;   // one 8-elem chunk
    if (i < 2 * NPAD) sums[i] = 0.0f;
    if (i == 0) *max_u = 0u;
    const int CPM = NPAD * (KDIM / 8);               // chunks per matrix
    if (i >= 2 * CPM) return;
    int mat = i / CPM;
    int rem = i - mat * CPM;
    int row = rem >> 5;          // KDIM/8 = 32 chunks per row
    int c8  = rem & 31;
    ushort4 lo = {0, 0, 0, 0}, hi = {0, 0, 0, 0};
    if (row < NPIX) {
        const float* src = x + (size_t)mat * NPIX * KDIM + (size_t)row * KDIM + c8 * 8;
        float4 v0 = reinterpret_cast<const float4*>(src)[0];
        float4 v1 = reinterpret_cast<const float4*>(src)[1];
        lo = ushort4{ f2bf(v0.x), f2bf(v0.y), f2bf(v0.z), f2bf(v0.w) };
        hi = ushort4{ f2bf(v1.x), f2bf(v1.y), f2bf(v1.z), f2bf(v1.w) };
    }
    unsigned short* d = (mat ? Bbf : Abf) + (size_t)row * KDIM + c8 * 8;
    reinterpret_cast<ushort4*>(d)[0] = lo;
    reinterpret_cast<ushort4*>(d)[1] = hi;
}

// D = A*B^T (5376^2 padded, K=256), 256x256 tiles, 8 waves (2x4) each 128x64.
// BK=64 double-buffered; stage(t+1) issued BEFORE compute(t) so the L2
// round-trip hides under ~2400cy of MFMA; one barrier per K-tile.
// LDS swizzle: 16B chunk c of row r at slot c^(r&7).
__global__ __launch_bounds__(512, 2) void gemm_reduce(
        const unsigned short* __restrict__ Abf, const unsigned short* __restrict__ Bbf,
        float* __restrict__ row_sum, float* __restrict__ col_sum,
        unsigned int* __restrict__ max_u) {
    __shared__ char lds[2 * BUFB];        // 128 KiB

    const int tid  = threadIdx.x;
    const int wave = tid >> 6, lane = tid & 63;

    // bijective XCD chunk swizzle (441 = 8*55 + 1)
    const int wg = blockIdx.x;
    const int q = NWG >> 3, r8 = NWG & 7;
    const int xcd = wg & 7, cidx = wg >> 3;
    const int swz = (xcd < r8) ? xcd * (q + 1) + cidx
                               : r8 * (q + 1) + (xcd - r8) * q + cidx;
    const int brow = (swz / NT) * BT;
    const int bcol = (swz % NT) * BT;

    const char* Ag = (const char*)Abf;
    const char* Bg = (const char*)Bbf;

    // stage K-tile t into buffer d: 8 global_load_lds(16B)/thread = 64 KB
    auto stage = [&](int t, int d) {
        char* Ab = lds + d * BUFB;
        char* Bb = Ab + MATB;
        #pragma unroll
        for (int j = 0; j < 4; ++j) {
            int base = wave * 4096 + j * 1024;       // wave-uniform LDS dest
            int p    = base + lane * 16;
            int row  = p >> 7;                       // 128 B per row
            int c    = ((p >> 4) & 7) ^ (row & 7);   // pre-swizzled src chunk
            __builtin_amdgcn_global_load_lds(
                (const __attribute__((address_space(1))) unsigned int*)
                    (Ag + (size_t)(brow + row) * 512 + t * 128 + (c << 4)),
                (__attribute__((address_space(3))) unsigned int*)(Ab + base),
                16, 0, 0);
            __builtin_amdgcn_global_load_lds(
                (const __attribute__((address_space(1))) unsigned int*)
                    (Bg + (size_t)(bcol + row) * 512 + t * 128 + (c << 4)),
                (__attribute__((address_space(3))) unsigned int*)(Bb + base),
                16, 0, 0);
        }
    };

    stage(0, 0);
    __syncthreads();                      // drains vmcnt(0)

    const int wr = wave >> 2;   // 0..1  -> m block of 128 rows
    const int wc = wave & 3;    // 0..3  -> n block of 64 cols
    const int lr = lane & 15;
    const int lg = lane >> 4;   // 0..3

    f32x4 acc[8][4] = {};
    #pragma unroll
    for (int t = 0; t < NKT; ++t) {
        if (t + 1 < NKT) stage(t + 1, (t + 1) & 1);   // issue early (T14)
        const char* Ab = lds + (t & 1) * BUFB;
        const char* Bb = Ab + MATB;
        #pragma unroll
        for (int ksl = 0; ksl < 2; ++ksl) {
            int kc = ksl * 4 + lg;
            bf16x8 a[8], b[4];
            #pragma unroll
            for (int m = 0; m < 8; ++m) {
                int r = wr * 128 + m * 16 + lr;
                a[m] = *reinterpret_cast<const bf16x8*>(Ab + r * 128 + ((kc ^ (r & 7)) << 4));
            }
            #pragma unroll
            for (int n = 0; n < 4; ++n) {
                int r = wc * 64 + n * 16 + lr;
                b[n] = *reinterpret_cast<const bf16x8*>(Bb + r * 128 + ((kc ^ (r & 7)) << 4));
            }
            #pragma unroll
            for (int m = 0; m < 8; ++m)
                #pragma unroll
                for (int n = 0; n < 4; ++n)
                    acc[m][n] = __builtin_amdgcn_mfma_f32_16x16x32_bf16(a[m], b[n], acc[m][n], 0, 0, 0);
        }
        __syncthreads();        // retires buf reads + drains stage(t+1)
    }

    // ---- fused reductions. C/D: col = lane&15, row = (lane>>4)*4 + reg ----
    float mx = -3.4e38f;
    float cs[4] = {};
    float rs[32];
    #pragma unroll
    for (int j = 0; j < 32; ++j) rs[j] = 0.0f;
    #pragma unroll
    for (int m = 0; m < 8; ++m)
        #pragma unroll
        for (int n = 0; n < 4; ++n)
            #pragma unroll
            for (int r = 0; r < 4; ++r) {
                float v = acc[m][n][r];
                mx = fmaxf(mx, v);
                float rv = fmaxf(v, 0.0f);
                cs[n] += rv;
                rs[m * 4 + r] += rv;
            }

    // col sums: reduce over lane groups (rows), lanes 0..15 hold cols
    #pragma unroll
    for (int n = 0; n < 4; ++n) {
        cs[n] += __shfl_xor(cs[n], 16);
        cs[n] += __shfl_xor(cs[n], 32);
    }
    if (lane < 16) {
        #pragma unroll
        for (int n = 0; n < 4; ++n)
            atomicAdd(&col_sum[bcol + wc * 64 + n * 16 + lane], cs[n]);
    }

    // row sums: butterfly across the 16 col-lanes within each lane group
    #pragma unroll
    for (int off = 1; off <= 8; off <<= 1)
        #pragma unroll
        for (int j = 0; j < 32; ++j)
            rs[j] += __shfl_xor(rs[j], off);
    if (lr == 0) {
        int rbase = brow + wr * 128 + lg * 4;
        #pragma unroll
        for (int m = 0; m < 8; ++m)
            #pragma unroll
            for (int r = 0; r < 4; ++r)
                atomicAdd(&row_sum[rbase + m * 16 + r], rs[m * 4 + r]);
    }

    // block max -> one atomicMax
    #pragma unroll
    for (int off = 32; off >= 1; off >>= 1)
        mx = fmaxf(mx, __shfl_xor(mx, off));
    float* smax = reinterpret_cast<float*>(lds);
    if (lane == 0) smax[wave] = mx;
    __syncthreads();
    if (tid == 0) {
        float m8 = smax[0];
        #pragma unroll
        for (int w = 1; w < 8; ++w) m8 = fmaxf(m8, smax[w]);
        atomicMax(max_u, fmono(m8));
    }
}

// Bilinear resize 2x72x72 -> 2x224x224 with final /max (resize is linear).
__global__ void finalize(const float* __restrict__ row_sum,
                         const float* __restrict__ col_sum,
                         const unsigned int* __restrict__ max_u,
                         float* __restrict__ out) {
    int o = blockIdx.x * blockDim.x + threadIdx.x;
    if (o >= 2 * OUTHW * OUTHW) return;
    int img = o / (OUTHW * OUTHW);
    int rem = o % (OUTHW * OUTHW);
    int oy = rem / OUTHW, ox = rem % OUTHW;
    const float* src = (img == 0) ? row_sum : col_sum;
    float inv = 1.0f / funmono(*max_u);

    const float s = 72.0f / 224.0f;
    float ys = fmaxf(((float)oy + 0.5f) * s - 0.5f, 0.0f);
    float xs = fmaxf(((float)ox + 0.5f) * s - 0.5f, 0.0f);
    int y0 = (int)floorf(ys), x0 = (int)floorf(xs);
    int y1 = min(y0 + 1, 71), x1 = min(x0 + 1, 71);
    float wy = ys - (float)y0, wx = xs - (float)x0;

    float a = src[y0 * 72 + x0], b = src[y0 * 72 + x1];
    float c = src[y1 * 72 + x0], d = src[y1 * 72 + x1];
    float v = a * (1.0f - wy) * (1.0f - wx) + b * (1.0f - wy) * wx
            + c * wy * (1.0f - wx)          + d * wy * wx;
    out[o] = v * inv;
}

extern "C" void kernel_launch(void* const* d_in, const int* in_sizes, int n_in,
                              void* d_out, int out_size, void* d_ws, size_t ws_size,
                              hipStream_t stream) {
    const float* X = (const float*)d_in[0];
    float* out = (float*)d_out;

    unsigned short* Abf = (unsigned short*)d_ws;
    unsigned short* Bbf = Abf + (size_t)NPAD * KDIM;
    float* row_sum      = (float*)(Bbf + (size_t)NPAD * KDIM);
    float* col_sum      = row_sum + NPAD;
    unsigned int* max_u = (unsigned int*)(col_sum + NPAD);

    int nthr = 2 * NPAD * (KDIM / 8);    // 344064 chunk threads
    convert_pad_bf16<<<(nthr + 255) / 256, 256, 0, stream>>>(X, Abf, Bbf, row_sum, max_u);
    gemm_reduce<<<NWG, 512, 0, stream>>>(Abf, Bbf, row_sum, col_sum, max_u);
    finalize<<<(2 * OUTHW * OUTHW + 255) / 256, 256, 0, stream>>>(row_sum, col_sum, max_u, out);
}